// Round 10
// baseline (182.419 us; speedup 1.0000x reference)
//
#include <hip/hip_runtime.h>
#include <hip/hip_bf16.h>
#include <math.h>

// Problem dims (fixed by reference)
#define B   32
#define P   196      // hw tokens (14x14)
#define C   768
#define NC  4096
#define HH  14
#define KSPLIT 24    // 768 / 32

typedef _Float16 half8 __attribute__((ext_vector_type(8)));
typedef _Float16 half4 __attribute__((ext_vector_type(4)));
typedef float f32x4 __attribute__((ext_vector_type(4)));

// ---------------------------------------------------------------------------
// K1: SpaceSelfAware + space_fusion + residual.  (unchanged)
// ---------------------------------------------------------------------------
__global__ __launch_bounds__(256) void k_ssa(const float* __restrict__ t,
                                             float* __restrict__ pre) {
    const int b = blockIdx.y, c0 = blockIdx.x * 32;
    __shared__ float xp_[256 * 32];        // [(i+2)*16 + (j+1)][cc]
    __shared__ float part[8][9][32];
    __shared__ float inv_norm[9][32];
    const int tid = threadIdx.x;
    const int cc = tid & 31, g = tid >> 5;

#pragma unroll
    for (int q = 0; q < 32; ++q) xp_[q * 256 + tid] = 0.0f;
    __syncthreads();

    for (int idx = tid; idx < (P * 32) / 4; idx += 256) {
        const int f = idx * 4;
        const int p = f >> 5, c = f & 31;
        const int i = p / HH, j = p % HH;
        *(float4*)&xp_[((i + 2) * 16 + (j + 1)) * 32 + c] =
            *(const float4*)&t[((size_t)b * P + p) * C + c0 + c];
    }
    __syncthreads();

    float s[9] = {};
    {
        int i = 0, j = g;
        for (int p = g; p < P; p += 8) {
            const int base = ((i + 2) * 16 + (j + 1)) * 32 + cc;
            const float xp = xp_[base];
            const float xp2 = xp * xp;
#pragma unroll
            for (int k = 0; k < 9; ++k) {
                const int off = ((k / 3) - 2) * 16 + (k % 3) - 1;  // const
                const float nb = xp_[base + off * 32];
                s[k] += xp2 * nb * nb;
            }
            j += 8;
            if (j >= HH) { j -= HH; ++i; }
        }
    }
#pragma unroll
    for (int k = 0; k < 9; ++k) part[g][k][cc] = s[k];
    __syncthreads();
    for (int k = g; k < 9; k += 8) {
        float t4 = 0.0f;
#pragma unroll
        for (int q = 0; q < 8; ++q) t4 += part[q][k][cc];
        inv_norm[k][cc] = 1.0f / fmaxf(sqrtf(t4), 1e-12f);
    }
    __syncthreads();

    float invn[9];
#pragma unroll
    for (int k = 0; k < 9; ++k) invn[k] = inv_norm[k][cc];

    {
        int i = 0, j = g;
        for (int p = g; p < P; p += 8) {
            const int base = ((i + 2) * 16 + (j + 1)) * 32 + cc;
            const float xp = xp_[base];
            float acc = 0.0f;
#pragma unroll
            for (int k = 0; k < 9; ++k) {
                const int off = ((k / 3) - 2) * 16 + (k % 3) - 1;
                const float v = xp * xp_[base + off * 32];
                const float u = fmaxf(v * invn[k], 1e-6f);
                acc += u * u * u;
            }
            pre[((size_t)b * P + p) * C + c0 + cc] =
                cbrtf(acc * (1.0f / 9.0f)) + xp;
            j += 8;
            if (j >= HH) { j -= HH; ++i; }
        }
    }
}

// ---------------------------------------------------------------------------
// K2: L2 normalize each (b,p) row over 768 channels; write f16 tokens.
// ---------------------------------------------------------------------------
__global__ __launch_bounds__(256) void k_rownorm(const float* __restrict__ in,
                                                 _Float16* __restrict__ out) {
    const int row = blockIdx.x;               // b*P + p
    const float* r = in + (size_t)row * C;
    const int tid = threadIdx.x;
    float vals[3];
    float s = 0.0f;
#pragma unroll
    for (int q = 0; q < 3; ++q) {
        vals[q] = r[tid + q * 256];
        s += vals[q] * vals[q];
    }
    __shared__ float partial[4];
    __shared__ float inv;
#pragma unroll
    for (int off = 32; off > 0; off >>= 1) s += __shfl_xor(s, off);
    if ((tid & 63) == 0) partial[tid >> 6] = s;
    __syncthreads();
    if (tid == 0)
        inv = 1.0f / fmaxf(sqrtf(partial[0] + partial[1] + partial[2] + partial[3]), 1e-12f);
    __syncthreads();
    _Float16* o = out + (size_t)row * C;
#pragma unroll
    for (int q = 0; q < 3; ++q) o[tid + q * 256] = (_Float16)(vals[q] * inv);
}

// ---------------------------------------------------------------------------
// K2b: weight transpose + f32->f16:  W (K x N) -> Wt (N x K)
// ---------------------------------------------------------------------------
__global__ __launch_bounds__(256) void k_wt(const float* __restrict__ W,
                                            _Float16* __restrict__ Wt) {
    __shared__ float t[32][33];
    const int k0 = blockIdx.x * 32, n0 = blockIdx.y * 32;
    const int r = threadIdx.x / 32, c = threadIdx.x % 32;
#pragma unroll
    for (int q = 0; q < 4; ++q)
        t[r + q * 8][c] = W[(size_t)(k0 + r + q * 8) * C + n0 + c];
    __syncthreads();
#pragma unroll
    for (int q = 0; q < 4; ++q)
        Wt[(size_t)(n0 + r + q * 8) * C + k0 + c] = (_Float16)t[c][r + q * 8];
}

// ---------------------------------------------------------------------------
// K3/K4: f16 MFMA GEMM, no LDS / no barriers, MANUAL 4-stage register
// pipeline (rule #20: named sets W/X/Y/Z, static indexing, unroll-by-4).
// Each sub-step issues one stage's 4 global fragment loads then MFMAs a
// stage loaded 3 sub-steps earlier -> ~12 loads in flight/wave, compiler
// emits counted vmcnt per register dep (never a full drain).
// ~100 VGPR; __launch_bounds__(256,4) caps at 128 -> ~16 waves/CU.
// Wt (1.2 MB) L2-resident; Tok XCD-local via swizzle.  Grid 1176 1-D.
// ---------------------------------------------------------------------------
template <bool GELU>
__global__ __launch_bounds__(256, 4) void k_mfma_gemm(
    const _Float16* __restrict__ Tok,   // (M=6272, K=768)  B-operand
    const _Float16* __restrict__ Wt,    // (N=768,  K=768)  A-operand
    const float* __restrict__ bias,     // (N)
    void* __restrict__ Cout) {          // f16 (GELU) or f32
    const int tid = threadIdx.x;
    const int w = tid >> 6, l = tid & 63;
    const int l15 = l & 15, lk = l >> 4;

    // XCD swizzle: lid -> (vm, vn)
    const int lid = blockIdx.x;
    int vm, vn;
    if (lid < 1152) { vm = (lid / 96) * 8 + (lid & 7); vn = (lid % 96) >> 3; }
    else            { const int r = lid - 1152; vm = 96 + r / 12; vn = r % 12; }
    const int m0 = vm * 64, n0 = vn * 64;
    const int wn = (w & 1) * 32, wm = (w >> 1) * 32;

    f32x4 acc[2][2] = {};   // [fa over n][fb over m]

    // per-lane fragment base pointers (16B-aligned, row stride 1536 B)
    const _Float16* pA0 = Wt  + (size_t)(n0 + wn + l15) * C + lk * 8;
    const _Float16* pA1 = pA0 + (size_t)16 * C;
    const _Float16* pB0 = Tok + (size_t)(m0 + wm + l15) * C + lk * 8;
    const _Float16* pB1 = pB0 + (size_t)16 * C;

#define LOADSET(s, t_)                                                         \
    {   const int kt_ = (t_) * 32;                                             \
        a0##s = *(const half8*)(pA0 + kt_);                                    \
        a1##s = *(const half8*)(pA1 + kt_);                                    \
        b0##s = *(const half8*)(pB0 + kt_);                                    \
        b1##s = *(const half8*)(pB1 + kt_); }
#define MFMASET(s)                                                             \
    {   acc[0][0] = __builtin_amdgcn_mfma_f32_16x16x32_f16(a0##s, b0##s, acc[0][0], 0, 0, 0); \
        acc[0][1] = __builtin_amdgcn_mfma_f32_16x16x32_f16(a0##s, b1##s, acc[0][1], 0, 0, 0); \
        acc[1][0] = __builtin_amdgcn_mfma_f32_16x16x32_f16(a1##s, b0##s, acc[1][0], 0, 0, 0); \
        acc[1][1] = __builtin_amdgcn_mfma_f32_16x16x32_f16(a1##s, b1##s, acc[1][1], 0, 0, 0); }

    half8 a0W, a1W, b0W, b1W, a0X, a1X, b0X, b1X;
    half8 a0Y, a1Y, b0Y, b1Y, a0Z, a1Z, b0Z, b1Z;

    LOADSET(W, 0); LOADSET(X, 1); LOADSET(Y, 2);
#pragma unroll
    for (int tt = 0; tt < 6; ++tt) {
        const int t = 4 * tt;
        LOADSET(Z, t + 3);                 // always valid (t+3 <= 23)
        MFMASET(W);
        if (tt < 5) LOADSET(W, t + 4);
        MFMASET(X);
        if (tt < 5) LOADSET(X, t + 5);
        MFMASET(Y);
        if (tt < 5) LOADSET(Y, t + 6);
        MFMASET(Z);
    }
#undef LOADSET
#undef MFMASET

    // epilogue: lane holds D[n = nb + r][m], r=0..3 consecutive n
#pragma unroll
    for (int fa = 0; fa < 2; ++fa) {
        const int nb = n0 + wn + fa * 16 + lk * 4;
        const float4 bv = *(const float4*)&bias[nb];
#pragma unroll
        for (int fb = 0; fb < 2; ++fb) {
            const int m = m0 + wm + fb * 16 + l15;
            if (GELU) {
                half4 o;
#pragma unroll
                for (int r = 0; r < 4; ++r) {
                    float v = acc[fa][fb][r] + ((const float*)&bv)[r];
                    v = 0.5f * v * (1.0f + erff(v * 0.70710678118654752f));
                    o[r] = (_Float16)v;
                }
                *(half4*)&((_Float16*)Cout)[(size_t)m * C + nb] = o;
            } else {
                float4 o;
#pragma unroll
                for (int r = 0; r < 4; ++r)
                    ((float*)&o)[r] = acc[fa][fb][r] + ((const float*)&bv)[r];
                *(float4*)&((float*)Cout)[(size_t)m * C + nb] = o;
            }
        }
    }
}

// ---------------------------------------------------------------------------
// K5: GeM over tokens: g[b,c] = (mean_p clip(x,1e-6)^3)^(1/3)
// ---------------------------------------------------------------------------
__global__ __launch_bounds__(256) void k_gempool(const float* __restrict__ tk,
                                                 float* __restrict__ g) {
    const int b = blockIdx.x / 3;
    const int c = (blockIdx.x % 3) * 256 + threadIdx.x;
    float s = 0.0f;
#pragma unroll 4
    for (int p = 0; p < P; ++p) {
        const float v = fmaxf(tk[((size_t)b * P + p) * C + c], 1e-6f);
        s += v * v * v;
    }
    g[b * C + c] = cbrtf(s * (1.0f / (float)P));
}

// ---------------------------------------------------------------------------
// K6a: head GEMM stage 1 (split-K).  grid (NC/64, KSPLIT) = 1536 blocks.
// ---------------------------------------------------------------------------
__global__ __launch_bounds__(256) void k_head1(const float* __restrict__ g,
                                               const float* __restrict__ W,
                                               float* __restrict__ partial) {
    const int n0 = blockIdx.x * 64;
    const int k0 = blockIdx.y * 32;
    __shared__ float gs[32][32];          // [b][kk]
    __shared__ float part[4][32][64];     // [q][b][c]
    const int tid = threadIdx.x;

    for (int idx = tid; idx < 32 * 32; idx += 256)
        gs[idx >> 5][idx & 31] = g[(idx >> 5) * C + k0 + (idx & 31)];
    __syncthreads();

    const int c = tid & 63, q = tid >> 6;
    float acc[32] = {};
#pragma unroll
    for (int kk = 0; kk < 8; ++kk) {
        const int k = q * 8 + kk;
        const float wv = W[(size_t)(k0 + k) * NC + n0 + c];
#pragma unroll
        for (int b = 0; b < 32; ++b) acc[b] += gs[b][k] * wv;
    }
#pragma unroll
    for (int b = 0; b < 32; ++b) part[q][b][c] = acc[b];
    __syncthreads();

    for (int o = tid; o < 32 * 64; o += 256) {
        const int b = o >> 6, cc = o & 63;
        const float v = part[0][b][cc] + part[1][b][cc] +
                        part[2][b][cc] + part[3][b][cc];
        partial[((size_t)blockIdx.y * 32 + b) * NC + n0 + cc] = v;
    }
}

// ---------------------------------------------------------------------------
// K6b: head GEMM stage 2: fixed-order sum of KSPLIT partials + bias.
// ---------------------------------------------------------------------------
__global__ __launch_bounds__(256) void k_head2(const float* __restrict__ partial,
                                               const float* __restrict__ hb,
                                               float* __restrict__ out) {
    const int n = blockIdx.x * 256 + threadIdx.x;
    const int b = blockIdx.y;
    float s = hb[n];
#pragma unroll
    for (int ks = 0; ks < KSPLIT; ++ks)
        s += partial[((size_t)ks * 32 + b) * NC + n];
    out[(size_t)b * NC + n] = s;
}

// ---------------------------------------------------------------------------
// K7: L2-normalize each batch row of out (4096) in place.
// ---------------------------------------------------------------------------
__global__ __launch_bounds__(256) void k_outnorm(float* __restrict__ out) {
    const int b = blockIdx.x;
    float* r = out + (size_t)b * NC;
    const int tid = threadIdx.x;
    float v[16];
    float s = 0.0f;
#pragma unroll
    for (int q = 0; q < 16; ++q) {
        v[q] = r[tid + q * 256];
        s += v[q] * v[q];
    }
    __shared__ float partial[4];
    __shared__ float inv;
#pragma unroll
    for (int off = 32; off > 0; off >>= 1) s += __shfl_xor(s, off);
    if ((tid & 63) == 0) partial[tid >> 6] = s;
    __syncthreads();
    if (tid == 0)
        inv = 1.0f / fmaxf(sqrtf(partial[0] + partial[1] + partial[2] + partial[3]), 1e-12f);
    __syncthreads();
#pragma unroll
    for (int q = 0; q < 16; ++q) r[tid + q * 256] = v[q] * inv;
}

// ---------------------------------------------------------------------------
extern "C" void kernel_launch(void* const* d_in, const int* in_sizes, int n_in,
                              void* d_out, int out_size, void* d_ws, size_t ws_size,
                              hipStream_t stream) {
    const float* patch  = (const float*)d_in[0];
    const float* fc1_w  = (const float*)d_in[1];
    const float* fc1_b  = (const float*)d_in[2];
    const float* fc2_w  = (const float*)d_in[3];
    const float* fc2_b  = (const float*)d_in[4];
    const float* head_w = (const float*)d_in[5];
    const float* head_b = (const float*)d_in[6];
    float* out = (float*)d_out;

    const size_t big = (size_t)B * P * C;        // 4,816,896 elements
    float*    pre  = (float*)d_ws;               // [big] f32; later reused as tok2
    _Float16* tokN = (_Float16*)(pre + big);     // [big] f16
    _Float16* hdn  = tokN + big;                 // [big] f16
    _Float16* wt1  = hdn + big;                  // [768*768] f16
    _Float16* wt2  = wt1 + C * C;                // [768*768] f16
    float*    gbuf = (float*)(wt2 + C * C);      // [32*768] f32
    float*    hpart = gbuf + B * C;              // [KSPLIT*32*4096] f32
    float*    tok2 = pre;                        // reuse

    // K1: SSA + fusion + residual -> pre
    k_ssa<<<dim3(C / 32, B), dim3(256), 0, stream>>>(patch, pre);
    // weight transposes (independent)
    k_wt<<<dim3(C / 32, C / 32), dim3(256), 0, stream>>>(fc1_w, wt1);
    k_wt<<<dim3(C / 32, C / 32), dim3(256), 0, stream>>>(fc2_w, wt2);
    // K2: channel L2 norm -> tokN (f16)
    k_rownorm<<<dim3(B * P), dim3(256), 0, stream>>>(pre, tokN);
    // K3: fc1 + gelu -> hdn (f16)
    k_mfma_gemm<true><<<dim3(1176), dim3(256), 0, stream>>>(
        tokN, wt1, fc1_b, hdn);
    // K4: fc2 -> tok2 (f32)
    k_mfma_gemm<false><<<dim3(1176), dim3(256), 0, stream>>>(
        hdn, wt2, fc2_b, tok2);
    // K5: GeM over tokens -> gbuf
    k_gempool<<<dim3(B * 3), dim3(256), 0, stream>>>(tok2, gbuf);
    // K6: head GEMM, split-K two-stage -> out (pre-normalized)
    k_head1<<<dim3(NC / 64, KSPLIT), dim3(256), 0, stream>>>(gbuf, head_w, hpart);
    k_head2<<<dim3(NC / 256, B), dim3(256), 0, stream>>>(hpart, head_b, out);
    // K7: normalize rows of out
    k_outnorm<<<dim3(B), dim3(256), 0, stream>>>(out);
}

// Round 11
// 104.118 us; speedup vs baseline: 1.7520x; 1.7520x over previous
//
#include <hip/hip_runtime.h>
#include <hip/hip_bf16.h>
#include <math.h>

// Problem dims (fixed by reference)
#define B   32
#define P   196      // hw tokens (14x14)
#define C   768
#define NC  4096
#define HH  14
#define KSPLIT 24    // 768 / 32
#define NT  12       // K tiles per GEMM (768 / 64)
#define M6  6272     // B*P
#define TW  (768 * 32)    // Wt packed tile stride (elements)
#define TM  (M6 * 32)     // Tok/hdn packed tile stride (elements)

typedef _Float16 half8 __attribute__((ext_vector_type(8)));
typedef _Float16 half4 __attribute__((ext_vector_type(4)));
typedef float f32x4 __attribute__((ext_vector_type(4)));

#define GLOAD_LDS16(g, l)                                                      \
    __builtin_amdgcn_global_load_lds(                                          \
        (const __attribute__((address_space(1))) void*)(g),                    \
        (__attribute__((address_space(3))) void*)(l), 16, 0, 0)

// ---------------------------------------------------------------------------
// K1: SpaceSelfAware + space_fusion + residual.  (unchanged)
// ---------------------------------------------------------------------------
__global__ __launch_bounds__(256) void k_ssa(const float* __restrict__ t,
                                             float* __restrict__ pre) {
    const int b = blockIdx.y, c0 = blockIdx.x * 32;
    __shared__ float xp_[256 * 32];        // [(i+2)*16 + (j+1)][cc]
    __shared__ float part[8][9][32];
    __shared__ float inv_norm[9][32];
    const int tid = threadIdx.x;
    const int cc = tid & 31, g = tid >> 5;

#pragma unroll
    for (int q = 0; q < 32; ++q) xp_[q * 256 + tid] = 0.0f;
    __syncthreads();

    for (int idx = tid; idx < (P * 32) / 4; idx += 256) {
        const int f = idx * 4;
        const int p = f >> 5, c = f & 31;
        const int i = p / HH, j = p % HH;
        *(float4*)&xp_[((i + 2) * 16 + (j + 1)) * 32 + c] =
            *(const float4*)&t[((size_t)b * P + p) * C + c0 + c];
    }
    __syncthreads();

    float s[9] = {};
    {
        int i = 0, j = g;
        for (int p = g; p < P; p += 8) {
            const int base = ((i + 2) * 16 + (j + 1)) * 32 + cc;
            const float xp = xp_[base];
            const float xp2 = xp * xp;
#pragma unroll
            for (int k = 0; k < 9; ++k) {
                const int off = ((k / 3) - 2) * 16 + (k % 3) - 1;  // const
                const float nb = xp_[base + off * 32];
                s[k] += xp2 * nb * nb;
            }
            j += 8;
            if (j >= HH) { j -= HH; ++i; }
        }
    }
#pragma unroll
    for (int k = 0; k < 9; ++k) part[g][k][cc] = s[k];
    __syncthreads();
    for (int k = g; k < 9; k += 8) {
        float t4 = 0.0f;
#pragma unroll
        for (int q = 0; q < 8; ++q) t4 += part[q][k][cc];
        inv_norm[k][cc] = 1.0f / fmaxf(sqrtf(t4), 1e-12f);
    }
    __syncthreads();

    float invn[9];
#pragma unroll
    for (int k = 0; k < 9; ++k) invn[k] = inv_norm[k][cc];

    {
        int i = 0, j = g;
        for (int p = g; p < P; p += 8) {
            const int base = ((i + 2) * 16 + (j + 1)) * 32 + cc;
            const float xp = xp_[base];
            float acc = 0.0f;
#pragma unroll
            for (int k = 0; k < 9; ++k) {
                const int off = ((k / 3) - 2) * 16 + (k % 3) - 1;
                const float v = xp * xp_[base + off * 32];
                const float u = fmaxf(v * invn[k], 1e-6f);
                acc += u * u * u;
            }
            pre[((size_t)b * P + p) * C + c0 + cc] =
                cbrtf(acc * (1.0f / 9.0f)) + xp;
            j += 8;
            if (j >= HH) { j -= HH; ++i; }
        }
    }
}

// ---------------------------------------------------------------------------
// K2: L2 normalize each (b,p) row over 768 channels; write f16 tokens in
// PACKED k-tiled layout: tokP[kb][row][k'] (kb=c>>5, k'=c&31).
// ---------------------------------------------------------------------------
__global__ __launch_bounds__(256) void k_rownorm(const float* __restrict__ in,
                                                 _Float16* __restrict__ outP) {
    const int row = blockIdx.x;               // b*P + p
    const float* r = in + (size_t)row * C;
    const int tid = threadIdx.x;
    float vals[3];
    float s = 0.0f;
#pragma unroll
    for (int q = 0; q < 3; ++q) {
        vals[q] = r[tid + q * 256];
        s += vals[q] * vals[q];
    }
    __shared__ float partial[4];
    __shared__ float inv;
#pragma unroll
    for (int off = 32; off > 0; off >>= 1) s += __shfl_xor(s, off);
    if ((tid & 63) == 0) partial[tid >> 6] = s;
    __syncthreads();
    if (tid == 0)
        inv = 1.0f / fmaxf(sqrtf(partial[0] + partial[1] + partial[2] + partial[3]), 1e-12f);
    __syncthreads();
#pragma unroll
    for (int q = 0; q < 3; ++q) {
        const int c = tid + q * 256;
        outP[(size_t)(c >> 5) * TM + (size_t)row * 32 + (c & 31)] =
            (_Float16)(vals[q] * inv);
    }
}

// ---------------------------------------------------------------------------
// K2b: weight pack: W (K x N) f32 -> WtP packed [kb][n][32] f16
// ---------------------------------------------------------------------------
__global__ __launch_bounds__(256) void k_wt(const float* __restrict__ W,
                                            _Float16* __restrict__ WtP) {
    __shared__ float t[32][33];
    const int k0 = blockIdx.x * 32, n0 = blockIdx.y * 32;
    const int r = threadIdx.x / 32, c = threadIdx.x % 32;
#pragma unroll
    for (int q = 0; q < 4; ++q)
        t[r + q * 8][c] = W[(size_t)(k0 + r + q * 8) * C + n0 + c];
    __syncthreads();
#pragma unroll
    for (int q = 0; q < 4; ++q)
        WtP[(size_t)blockIdx.x * TW + (size_t)(n0 + r + q * 8) * 32 + c] =
            (_Float16)t[c][r + q * 8];
}

// ---------------------------------------------------------------------------
// K3/K4: f16 MFMA GEMM, 3-deep counted-vmcnt pipeline (proven R7 sync
// structure) + PACKED k-tiled operands so every global_load_lds is fully
// coalesced: lane l reads src + l*16B within a contiguous 4 KB chunk
// (64 rows x 64 B).  No 64-line scatter -> no per-instr address stall.
// 64M x 64N tile, BK=64 (2 kb tiles/stage), 4 waves; wave w stages chunk
// {A/B} x {kb0/kb1}; LDS 3 x (2x64x32) x 2 ops = 48 KB -> 3 blocks/CU.
// Grid 1176 1-D with XCD swizzle.
// GELU=true: output hdn PACKED f16 [kb][m][32].  GELU=false: f32 row-major.
// ---------------------------------------------------------------------------
template <bool GELU>
__global__ __launch_bounds__(256) void k_mfma_gemm(
    const _Float16* __restrict__ TokP,  // packed (24 x M6 x 32)  B-operand
    const _Float16* __restrict__ WtP,   // packed (24 x 768 x 32) A-operand
    const float* __restrict__ bias,     // (N)
    void* __restrict__ Cout) {          // packed f16 (GELU) or f32 row-major
    __shared__ _Float16 lA[3][2][64][32];  // [buf][kb][n][k']
    __shared__ _Float16 lB[3][2][64][32];  // [buf][kb][m][k']
    const int tid = threadIdx.x;
    const int w = tid >> 6, l = tid & 63;
    const int l15 = l & 15, lk = l >> 4;

    // XCD swizzle: lid -> (vm, vn); equal lid%8 (one XCD) covers one m-row.
    const int lid = blockIdx.x;
    int vm, vn;
    if (lid < 1152) { vm = (lid / 96) * 8 + (lid & 7); vn = (lid % 96) >> 3; }
    else            { const int r = lid - 1152; vm = 96 + r / 12; vn = r % 12; }
    const int m0 = vm * 64, n0 = vn * 64;
    const int wn = (w & 1) * 32, wm = (w >> 1) * 32;

    f32x4 acc[2][2] = {};   // [fa over n][fb over m]

    // wave w stages one 4 KB chunk per stage: w<2 -> A (kb = w), else B
    const int kbsel = w & 1;
    const bool isB = (w >= 2);
    const _Float16* srcBase =
        isB ? (TokP + (size_t)m0 * 32) : (WtP + (size_t)n0 * 32);
    const size_t tileStride = isB ? (size_t)TM : (size_t)TW;
    _Float16* dst0 = isB ? &lB[0][kbsel][0][0] : &lA[0][kbsel][0][0];

#define ISSUE(tt, bf_)                                                         \
    {   const _Float16* s_ = srcBase + (size_t)(2 * (tt) + kbsel) * tileStride;\
        _Float16* d_ = dst0 + (size_t)(bf_) * 4096;                            \
        GLOAD_LDS16(s_ + l * 8,        d_ + l * 8);                            \
        GLOAD_LDS16(s_ + 512 + l * 8,  d_ + 512 + l * 8);                      \
        GLOAD_LDS16(s_ + 1024 + l * 8, d_ + 1024 + l * 8);                     \
        GLOAD_LDS16(s_ + 1536 + l * 8, d_ + 1536 + l * 8); }

    ISSUE(0, 0); ISSUE(1, 1); ISSUE(2, 2);   // 12 loads in flight / wave

    for (int t = 0; t < NT; ++t) {
        // own-wave tile-t loads complete; t+1, t+2 remain in flight
        if (t < NT - 2)       asm volatile("s_waitcnt vmcnt(8)" ::: "memory");
        else if (t == NT - 2) asm volatile("s_waitcnt vmcnt(4)" ::: "memory");
        else                  asm volatile("s_waitcnt vmcnt(0)" ::: "memory");
        __builtin_amdgcn_s_barrier();          // all waves' tile-t loads done
        __builtin_amdgcn_sched_barrier(0);     // no ds_read hoisted above

        const int buf = t % 3;
#pragma unroll
        for (int kk = 0; kk < 2; ++kk) {       // two 32-k sub-steps (kb tiles)
            half8 af[2], bf[2];
#pragma unroll
            for (int fa = 0; fa < 2; ++fa)
                af[fa] = *(const half8*)&lA[buf][kk][wn + fa * 16 + l15][lk * 8];
#pragma unroll
            for (int fb = 0; fb < 2; ++fb)
                bf[fb] = *(const half8*)&lB[buf][kk][wm + fb * 16 + l15][lk * 8];
#pragma unroll
            for (int fa = 0; fa < 2; ++fa)
#pragma unroll
                for (int fb = 0; fb < 2; ++fb)
                    acc[fa][fb] = __builtin_amdgcn_mfma_f32_16x16x32_f16(
                        af[fa], bf[fb], acc[fa][fb], 0, 0, 0);
        }
        asm volatile("s_waitcnt lgkmcnt(0)" ::: "memory");  // reads retired
        __builtin_amdgcn_s_barrier();          // safe to overwrite buf
        __builtin_amdgcn_sched_barrier(0);
        if (t < NT - 3) ISSUE(t + 3, buf);     // refill; stays in flight
    }
#undef ISSUE

    // epilogue: lane holds D[n = nb + r][m], r=0..3 consecutive n
#pragma unroll
    for (int fa = 0; fa < 2; ++fa) {
        const int nb = n0 + wn + fa * 16 + lk * 4;
        const float4 bv = *(const float4*)&bias[nb];
#pragma unroll
        for (int fb = 0; fb < 2; ++fb) {
            const int m = m0 + wm + fb * 16 + l15;
            if (GELU) {
                half4 o;
#pragma unroll
                for (int r = 0; r < 4; ++r) {
                    float v = acc[fa][fb][r] + ((const float*)&bv)[r];
                    v = 0.5f * v * (1.0f + erff(v * 0.70710678118654752f));
                    o[r] = (_Float16)v;
                }
                // packed write: hdnP[kb = nb>>5][m][k' = nb&31 .. +3]
                *(half4*)&((_Float16*)Cout)[(size_t)(nb >> 5) * TM +
                                            (size_t)m * 32 + (nb & 31)] = o;
            } else {
                float4 o;
#pragma unroll
                for (int r = 0; r < 4; ++r)
                    ((float*)&o)[r] = acc[fa][fb][r] + ((const float*)&bv)[r];
                *(float4*)&((float*)Cout)[(size_t)m * C + nb] = o;
            }
        }
    }
}

// ---------------------------------------------------------------------------
// K5: GeM over tokens: g[b,c] = (mean_p clip(x,1e-6)^3)^(1/3)
// ---------------------------------------------------------------------------
__global__ __launch_bounds__(256) void k_gempool(const float* __restrict__ tk,
                                                 float* __restrict__ g) {
    const int b = blockIdx.x / 3;
    const int c = (blockIdx.x % 3) * 256 + threadIdx.x;
    float s = 0.0f;
#pragma unroll 4
    for (int p = 0; p < P; ++p) {
        const float v = fmaxf(tk[((size_t)b * P + p) * C + c], 1e-6f);
        s += v * v * v;
    }
    g[b * C + c] = cbrtf(s * (1.0f / (float)P));
}

// ---------------------------------------------------------------------------
// K6a: head GEMM stage 1 (split-K).  grid (NC/64, KSPLIT) = 1536 blocks.
// ---------------------------------------------------------------------------
__global__ __launch_bounds__(256) void k_head1(const float* __restrict__ g,
                                               const float* __restrict__ W,
                                               float* __restrict__ partial) {
    const int n0 = blockIdx.x * 64;
    const int k0 = blockIdx.y * 32;
    __shared__ float gs[32][32];          // [b][kk]
    __shared__ float part[4][32][64];     // [q][b][c]
    const int tid = threadIdx.x;

    for (int idx = tid; idx < 32 * 32; idx += 256)
        gs[idx >> 5][idx & 31] = g[(idx >> 5) * C + k0 + (idx & 31)];
    __syncthreads();

    const int c = tid & 63, q = tid >> 6;
    float acc[32] = {};
#pragma unroll
    for (int kk = 0; kk < 8; ++kk) {
        const int k = q * 8 + kk;
        const float wv = W[(size_t)(k0 + k) * NC + n0 + c];
#pragma unroll
        for (int b = 0; b < 32; ++b) acc[b] += gs[b][k] * wv;
    }
#pragma unroll
    for (int b = 0; b < 32; ++b) part[q][b][c] = acc[b];
    __syncthreads();

    for (int o = tid; o < 32 * 64; o += 256) {
        const int b = o >> 6, cc = o & 63;
        const float v = part[0][b][cc] + part[1][b][cc] +
                        part[2][b][cc] + part[3][b][cc];
        partial[((size_t)blockIdx.y * 32 + b) * NC + n0 + cc] = v;
    }
}

// ---------------------------------------------------------------------------
// K6b: head GEMM stage 2: fixed-order sum of KSPLIT partials + bias.
// ---------------------------------------------------------------------------
__global__ __launch_bounds__(256) void k_head2(const float* __restrict__ partial,
                                               const float* __restrict__ hb,
                                               float* __restrict__ out) {
    const int n = blockIdx.x * 256 + threadIdx.x;
    const int b = blockIdx.y;
    float s = hb[n];
#pragma unroll
    for (int ks = 0; ks < KSPLIT; ++ks)
        s += partial[((size_t)ks * 32 + b) * NC + n];
    out[(size_t)b * NC + n] = s;
}

// ---------------------------------------------------------------------------
// K7: L2-normalize each batch row of out (4096) in place.
// ---------------------------------------------------------------------------
__global__ __launch_bounds__(256) void k_outnorm(float* __restrict__ out) {
    const int b = blockIdx.x;
    float* r = out + (size_t)b * NC;
    const int tid = threadIdx.x;
    float v[16];
    float s = 0.0f;
#pragma unroll
    for (int q = 0; q < 16; ++q) {
        v[q] = r[tid + q * 256];
        s += v[q] * v[q];
    }
    __shared__ float partial[4];
    __shared__ float inv;
#pragma unroll
    for (int off = 32; off > 0; off >>= 1) s += __shfl_xor(s, off);
    if ((tid & 63) == 0) partial[tid >> 6] = s;
    __syncthreads();
    if (tid == 0)
        inv = 1.0f / fmaxf(sqrtf(partial[0] + partial[1] + partial[2] + partial[3]), 1e-12f);
    __syncthreads();
#pragma unroll
    for (int q = 0; q < 16; ++q) r[tid + q * 256] = v[q] * inv;
}

// ---------------------------------------------------------------------------
extern "C" void kernel_launch(void* const* d_in, const int* in_sizes, int n_in,
                              void* d_out, int out_size, void* d_ws, size_t ws_size,
                              hipStream_t stream) {
    const float* patch  = (const float*)d_in[0];
    const float* fc1_w  = (const float*)d_in[1];
    const float* fc1_b  = (const float*)d_in[2];
    const float* fc2_w  = (const float*)d_in[3];
    const float* fc2_b  = (const float*)d_in[4];
    const float* head_w = (const float*)d_in[5];
    const float* head_b = (const float*)d_in[6];
    float* out = (float*)d_out;

    const size_t big = (size_t)B * P * C;        // 4,816,896 elements
    float*    pre  = (float*)d_ws;               // [big] f32; later reused as tok2
    _Float16* tokP = (_Float16*)(pre + big);     // [big] f16 packed
    _Float16* hdnP = tokP + big;                 // [big] f16 packed
    _Float16* wt1  = hdnP + big;                 // [768*768] f16 packed
    _Float16* wt2  = wt1 + C * C;                // [768*768] f16 packed
    float*    gbuf = (float*)(wt2 + C * C);      // [32*768] f32
    float*    hpart = gbuf + B * C;              // [KSPLIT*32*4096] f32
    float*    tok2 = pre;                        // reuse

    // K1: SSA + fusion + residual -> pre
    k_ssa<<<dim3(C / 32, B), dim3(256), 0, stream>>>(patch, pre);
    // weight packs (independent)
    k_wt<<<dim3(C / 32, C / 32), dim3(256), 0, stream>>>(fc1_w, wt1);
    k_wt<<<dim3(C / 32, C / 32), dim3(256), 0, stream>>>(fc2_w, wt2);
    // K2: channel L2 norm -> tokP (f16 packed)
    k_rownorm<<<dim3(B * P), dim3(256), 0, stream>>>(pre, tokP);
    // K3: fc1 + gelu -> hdnP (f16 packed)
    k_mfma_gemm<true><<<dim3(1176), dim3(256), 0, stream>>>(
        tokP, wt1, fc1_b, hdnP);
    // K4: fc2 -> tok2 (f32 row-major)
    k_mfma_gemm<false><<<dim3(1176), dim3(256), 0, stream>>>(
        hdnP, wt2, fc2_b, tok2);
    // K5: GeM over tokens -> gbuf
    k_gempool<<<dim3(B * 3), dim3(256), 0, stream>>>(tok2, gbuf);
    // K6: head GEMM, split-K two-stage -> out (pre-normalized)
    k_head1<<<dim3(NC / 64, KSPLIT), dim3(256), 0, stream>>>(gbuf, head_w, hpart);
    k_head2<<<dim3(NC / 256, B), dim3(256), 0, stream>>>(hpart, head_b, out);
    // K7: normalize rows of out
    k_outnorm<<<dim3(B), dim3(256), 0, stream>>>(out);
}